// Round 10
// baseline (187.592 us; speedup 1.0000x reference)
//
#include <hip/hip_runtime.h>

// RF grid-sample DAS beamforming.
// Shapes: d_tx[4,512,256] d_rx[128,512,256] apod[128,512,256] rf[4,128,3072] t0[4]
// out[4,512,256] fp32.
//
// R10 = R9 (69.4us: TPB=1024, 96KB double-buffer, 1 barrier/iter, stream
// prefetch in regs, VGPR 52 clean) + fp16-dup LDS staged via registers.
// Cycle model at R9: LDS pipe ~5.5k cyc/iter (3.0k gathers + 2.5k conflicts)
// = critical path; streams ~3.2k; VALU ~1.5k. fp16 DUPLICATED pairs
// (lds[s]={rf[s],rf[s+1]}, 4B) halve both gather wave-ops and conflicts
// (mechanism counter-verified in R3/R7). R7's null result was on the old
// lockstep structure where barriers dominated; doesn't transfer here.
// DMA can't convert, so staging is reg-mediated (T14): issue next-e rf loads
// at top of iter, interp current buffer (hides ~900cy latency), then
// convert+ds_write AFTER interp, single barrier. Registers are free at
// 1 block/CU (LDS-capped): 52 -> ~85 VGPR, cliff at 128.
// Lessons kept: lane-contiguous stride-TPB addressing (R6), ESPLIT=8,
// grid 32x8=256=1 block/CU exact.
// Litmus: conflicts ~5.2e6; FETCH ~91MB WRITE ~16MB (no spills).
// Partial sums via fp32 atomicAdd (out zeroed by memset; graph-capture safe).
// Data range: delay in [0,3070] => i1 <= 3071 = S-1: clamp no-op safety;
// duplicated pair at s=3071 (garbage second half) never read (i0<=3070).

#define A_N 4
#define E_N 128
#define S_N 3072
#define NPIX_N (512 * 256)
#define TPB 1024                   // threads per block (16 waves)
#define PXT 4                      // pixels per thread (stride-TPB)
#define TILE (TPB * PXT)           // 4096 pixels per block
#define TILES (NPIX_N / TILE)      // 32
#define ESPLIT 8                   // e-chunks
#define EPB (E_N / ESPLIT)         // 16 elements per block
#define SIT ((A_N * (S_N / 4)) / TPB)  // 3072 float4-slots / 1024 thr = 3

typedef __fp16 half2_t __attribute__((ext_vector_type(2)));

__global__ __launch_bounds__(TPB) void das_kernel(
    const float* __restrict__ d_tx, const float* __restrict__ d_rx,
    const float* __restrict__ apod, const float* __restrict__ rf,
    const float* __restrict__ t0,  float* __restrict__ out)
{
    __shared__ __align__(16) half2_t lds_rf[2][A_N * S_N];   // 2 x 48 KB
    const int tid = threadIdx.x;
    const int px0 = blockIdx.x * TILE + tid;   // + k*TPB for k in [0,PXT)
    const int e0  = blockIdx.y * EPB;

    // Per-thread staging slots (compile-time addressing).
    int s_a[SIT], s_s4[SIT];
#pragma unroll
    for (int j = 0; j < SIT; ++j) {
        int idx = tid + j * TPB;          // float4 slot 0..3071
        s_a[j]  = idx / (S_N / 4);        // 0..3
        s_s4[j] = idx - s_a[j] * (S_N / 4);  // 0..767
    }

    float4 pf[SIT];
    float  pe[SIT];
    auto load_rf = [&](int e) {
#pragma unroll
        for (int j = 0; j < SIT; ++j) {
            const float* r = rf + ((size_t)(s_a[j] * E_N + e)) * S_N + s_s4[j] * 4;
            pf[j] = *(const float4*)r;
            pe[j] = r[(s_s4[j] == (S_N / 4 - 1)) ? 3 : 4];
        }
    };
    auto write_rf = [&](int b) {
#pragma unroll
        for (int j = 0; j < SIT; ++j) {
            float4 v = pf[j];
            float  x = pe[j];
            union { half2_t h[4]; float4 f; } u;
            u.h[0] = half2_t{(__fp16)v.x, (__fp16)v.y};   // RNE converts
            u.h[1] = half2_t{(__fp16)v.y, (__fp16)v.z};
            u.h[2] = half2_t{(__fp16)v.z, (__fp16)v.w};
            u.h[3] = half2_t{(__fp16)v.w, (__fp16)x};
            *(float4*)&lds_rf[b][s_a[j] * S_N + s_s4[j] * 4] = u.f;
        }
    };

    load_rf(e0);   // prologue rf loads start immediately

    float acc[A_N][PXT];
    float dta[A_N][PXT];
#pragma unroll
    for (int a = 0; a < A_N; ++a) {
        const float t0a = t0[a];
#pragma unroll
        for (int k = 0; k < PXT; ++k) {
            dta[a][k] = d_tx[a * NPIX_N + px0 + k * TPB] - t0a;
            acc[a][k] = 0.0f;
        }
    }

    // Prologue stream loads for ei=0.
    float ndrx[PXT], nap[PXT];
#pragma unroll
    for (int k = 0; k < PXT; ++k) {
        ndrx[k] = d_rx[(size_t)e0 * NPIX_N + px0 + k * TPB];
        nap[k]  = apod[(size_t)e0 * NPIX_N + px0 + k * TPB];
    }

    write_rf(0);       // convert + LDS-write buffer 0
    __syncthreads();   // buffer 0 + prologue streams ready

    for (int ei = 0; ei < EPB; ++ei) {
        const int e   = e0 + ei;
        const int cur = ei & 1;

        // Current iteration's stream values (loaded last iteration).
        float drx[PXT], ap[PXT];
#pragma unroll
        for (int k = 0; k < PXT; ++k) { drx[k] = ndrx[k]; ap[k] = nap[k]; }

        // Issue next element's loads now (rf -> pf/pe regs, streams -> regs);
        // their latency hides under the interp loop below.
        if (ei + 1 < EPB) {
            load_rf(e + 1);
            const float* __restrict__ nd = d_rx + (size_t)(e + 1) * NPIX_N;
            const float* __restrict__ na = apod + (size_t)(e + 1) * NPIX_N;
#pragma unroll
            for (int k = 0; k < PXT; ++k) {
                ndrx[k] = nd[px0 + k * TPB];
                nap[k]  = na[px0 + k * TPB];
            }
        }

        // Interp: one ds_read_b32 per tap-pair, zero global-memory deps.
        const half2_t* __restrict__ L = lds_rf[cur];
#pragma unroll
        for (int k = 0; k < PXT; ++k) {
#pragma unroll
            for (int a = 0; a < A_N; ++a) {
                float delay = dta[a][k] + drx[k];
                float x0 = floorf(delay);
                float w  = delay - x0;
                int i0 = (int)x0;
                i0 = min(max(i0, 0), S_N - 2);   // no-op for this data; safety
                half2_t hv = L[a * S_N + i0];    // {v0, v1}
                float v0 = (float)hv[0];
                float v1 = (float)hv[1];
                acc[a][k] += (v0 + w * (v1 - v0)) * ap[k];
            }
        }

        // Write next buffer AFTER interp (loads have landed by now);
        // buf[cur^1]'s previous readers all passed the barrier ending ei-1.
        if (ei + 1 < EPB) write_rf(cur ^ 1);

        // Single barrier per iter: orders buffer swap; implicit waitcnt
        // drains any straggler loads/writes.
        __syncthreads();
    }

#pragma unroll
    for (int a = 0; a < A_N; ++a)
#pragma unroll
        for (int k = 0; k < PXT; ++k)
            atomicAdd(&out[a * NPIX_N + px0 + k * TPB], acc[a][k]);
}

extern "C" void kernel_launch(void* const* d_in, const int* in_sizes, int n_in,
                              void* d_out, int out_size, void* d_ws, size_t ws_size,
                              hipStream_t stream) {
    const float* d_tx = (const float*)d_in[0];
    const float* d_rx = (const float*)d_in[1];
    const float* apod = (const float*)d_in[2];
    const float* rf   = (const float*)d_in[3];
    const float* t0   = (const float*)d_in[4];
    float* out = (float*)d_out;

    hipMemsetAsync(out, 0, (size_t)out_size * sizeof(float), stream);
    dim3 grid(TILES, ESPLIT);
    das_kernel<<<grid, TPB, 0, stream>>>(d_tx, d_rx, apod, rf, t0, out);
}